// Round 2
// baseline (1797.585 us; speedup 1.0000x reference)
//
#include <hip/hip_runtime.h>

#define DD 128
#define DECAYF 0.1f
#define EPSF 1e-5f

typedef float floatx4 __attribute__((ext_vector_type(4)));

// workspace layout (byte offsets)
#define WS_E2   0            // K floats
#define WS_X2   (64 << 10)   // T floats
#define WS_CS   (256 << 10)  // K floats
#define WS_SUM  (320 << 10)  // 1 float
#define WS_PACK (384 << 10)  // T u64
#define WS_ES   (1 << 20)    // K*D floats

// one wave per row: sum of squares over D=128
__global__ void row_sumsq(const float* __restrict__ m, float* __restrict__ out, int nrows) {
    int wave = (blockIdx.x * blockDim.x + threadIdx.x) >> 6;
    int lane = threadIdx.x & 63;
    if (wave >= nrows) return;
    const float* r = m + (size_t)wave * DD;
    float a = r[lane], b = r[lane + 64];
    float v = a * a + b * b;
    for (int off = 32; off; off >>= 1) v += __shfl_down(v, off);
    if (lane == 0) out[wave] = v;
}

__global__ void sum_all(const float* __restrict__ in, int n, float* __restrict__ out) {
    __shared__ float s[256];
    float v = 0.f;
    for (int i = threadIdx.x; i < n; i += 256) v += in[i];
    s[threadIdx.x] = v;
    __syncthreads();
    for (int o = 128; o; o >>= 1) {
        if ((int)threadIdx.x < o) s[threadIdx.x] += s[threadIdx.x + o];
        __syncthreads();
    }
    if (threadIdx.x == 0) out[0] = s[0];
}

// SGEMM-shaped dist kernel: 128 tokens x 256 codes per block, BK=32, 256 threads.
// Per-thread micro-tile: 8 tokens x 16 codes (codes strided: tx*4 + q*64).
// As: token-major [128][32], d4-index XOR-swizzled by (tok>>3)&7  -> conflict-free reads.
// Bs: d-major [32][256], column XOR-swizzled by ((d>>2)&7)<<2     -> conflict-free reads,
//     2-way (free) scatter writes.
// dist = x2 + e2 - 2*x.e, fused packed (float_bits<<32|k) argmin via atomicMin.
#define BM 128
#define BN 256
#define BK 32

__launch_bounds__(256, 2)
__global__ void dist_kernel(const float* __restrict__ x, const float* __restrict__ e,
                            const float* __restrict__ x2w, const float* __restrict__ e2w,
                            float* __restrict__ dist,
                            unsigned long long* __restrict__ packed, int Kdim) {
    __shared__ __align__(16) float As[BM * BK];   // 16 KB
    __shared__ __align__(16) float Bs[BK * BN];   // 32 KB

    const int tid = threadIdx.x;
    const int tx = tid & 15;        // code group: codes tx*4 + q*64 + j
    const int ty = tid >> 4;        // token group: tokens ty*8 + i
    const int t0 = blockIdx.x * BM;
    const int c0 = blockIdx.y * BN;
    const int syt = ty & 7;

    float4 acc[8][4];
#pragma unroll
    for (int i = 0; i < 8; ++i)
#pragma unroll
        for (int q = 0; q < 4; ++q) acc[i][q] = make_float4(0.f, 0.f, 0.f, 0.f);

#pragma unroll 1
    for (int kk = 0; kk < 4; ++kk) {
        __syncthreads();
        // stage A: 128 tokens x 32 d, token-major, swizzled d4 index
#pragma unroll
        for (int s = 0; s < 4; ++s) {
            int f4 = s * 256 + tid;
            int tok = f4 >> 3;
            int c4 = f4 & 7;
            float4 v = *(const float4*)&x[(size_t)(t0 + tok) * DD + kk * BK + c4 * 4];
            int sw = c4 ^ ((tok >> 3) & 7);
            *(float4*)&As[tok * BK + sw * 4] = v;
        }
        // stage B transposed: [d][code], column-swizzled by (d>>2)<<2
#pragma unroll
        for (int s = 0; s < 8; ++s) {
            int f4 = s * 256 + tid;
            int code = f4 >> 3;
            int c4 = f4 & 7;                       // d4 within chunk
            float4 v = *(const float4*)&e[(size_t)(c0 + code) * DD + kk * BK + c4 * 4];
            int col = code ^ (c4 << 2);
            Bs[(c4 * 4 + 0) * BN + col] = v.x;
            Bs[(c4 * 4 + 1) * BN + col] = v.y;
            Bs[(c4 * 4 + 2) * BN + col] = v.z;
            Bs[(c4 * 4 + 3) * BN + col] = v.w;
        }
        __syncthreads();

#pragma unroll 2
        for (int d4 = 0; d4 < 8; ++d4) {
            float4 a[8];
#pragma unroll
            for (int i = 0; i < 8; ++i)
                a[i] = *(const float4*)&As[(ty * 8 + i) * BK + ((d4 ^ syt) << 2)];
            const int cswz = d4 << 2;
#pragma unroll
            for (int dd = 0; dd < 4; ++dd) {
                float4 b[4];
#pragma unroll
                for (int q = 0; q < 4; ++q) {
                    int col = (tx * 4 + q * 64) ^ cswz;
                    b[q] = *(const float4*)&Bs[(d4 * 4 + dd) * BN + col];
                }
#pragma unroll
                for (int i = 0; i < 8; ++i) {
                    float av = (dd == 0) ? a[i].x : (dd == 1) ? a[i].y : (dd == 2) ? a[i].z : a[i].w;
#pragma unroll
                    for (int q = 0; q < 4; ++q) {
                        acc[i][q].x = fmaf(av, b[q].x, acc[i][q].x);
                        acc[i][q].y = fmaf(av, b[q].y, acc[i][q].y);
                        acc[i][q].z = fmaf(av, b[q].z, acc[i][q].z);
                        acc[i][q].w = fmaf(av, b[q].w, acc[i][q].w);
                    }
                }
            }
        }
    }

    // epilogue: dist = x2 + e2 - 2*acc, nontemporal store, packed argmin
    float rx2[8];
#pragma unroll
    for (int i = 0; i < 8; ++i) rx2[i] = x2w[t0 + ty * 8 + i];

    unsigned long long pmin[8];
#pragma unroll
    for (int i = 0; i < 8; ++i) pmin[i] = ~0ull;

#pragma unroll
    for (int q = 0; q < 4; ++q) {
        const int cc = c0 + tx * 4 + q * 64;
        float4 re2 = *(const float4*)&e2w[cc];
#pragma unroll
        for (int i = 0; i < 8; ++i) {
            float dj[4];
            dj[0] = rx2[i] + re2.x - 2.f * acc[i][q].x;
            dj[1] = rx2[i] + re2.y - 2.f * acc[i][q].y;
            dj[2] = rx2[i] + re2.z - 2.f * acc[i][q].z;
            dj[3] = rx2[i] + re2.w - 2.f * acc[i][q].w;
            floatx4 dv = {dj[0], dj[1], dj[2], dj[3]};
            __builtin_nontemporal_store(dv, (floatx4*)&dist[(size_t)(t0 + ty * 8 + i) * Kdim + cc]);
#pragma unroll
            for (int j = 0; j < 4; ++j) {
                unsigned u = __float_as_uint(fmaxf(dj[j], 0.f));
                unsigned long long p = ((unsigned long long)u << 32) | (unsigned)(cc + j);
                pmin[i] = pmin[i] < p ? pmin[i] : p;
            }
        }
    }

    __syncthreads();
    unsigned long long* pm = (unsigned long long*)As;   // [16][128] = 16 KB, reuse As
#pragma unroll
    for (int i = 0; i < 8; ++i) pm[tx * BM + ty * 8 + i] = pmin[i];
    __syncthreads();
    if (tid < BM) {
        unsigned long long m = pm[tid];
#pragma unroll
        for (int s = 1; s < 16; ++s) {
            unsigned long long v = pm[s * BM + tid];
            m = m < v ? m : v;
        }
        atomicMin(&packed[t0 + tid], m);
    }
}

// per token: gather quantized, write index (as float), accumulate counts/sums
__global__ void assign_kernel(const float* __restrict__ x, const float* __restrict__ e,
                              const unsigned long long* __restrict__ packed,
                              float* __restrict__ q, float* __restrict__ idx_out,
                              float* __restrict__ cs, float* __restrict__ es) {
    int t = blockIdx.x * 2 + (threadIdx.x >> 7);
    int d = threadIdx.x & 127;
    int k = (int)(packed[t] & 0xffffffffull);
    q[(size_t)t * DD + d] = e[(size_t)k * DD + d];
    atomicAdd(&es[(size_t)k * DD + d], x[(size_t)t * DD + d]);
    if (d == 0) {
        idx_out[t] = (float)k;
        atomicAdd(&cs[k], 1.0f);
    }
}

__global__ void finalize_kernel(const float* __restrict__ cluster_size,
                                const float* __restrict__ embed_avg,
                                const float* __restrict__ cs, const float* __restrict__ es,
                                const float* __restrict__ sumcs,
                                float* __restrict__ out_embed, float* __restrict__ out_ncs,
                                float* __restrict__ out_nea, int Kdim, int T) {
    int g = blockIdx.x * 256 + threadIdx.x;
    int k = g >> 7;
    int d = g & 127;
    float S = DECAYF * sumcs[0] + (1.f - DECAYF) * (float)T;
    float denom = S + (float)Kdim * EPSF;
    float ncs = DECAYF * cluster_size[k] + (1.f - DECAYF) * cs[k];
    if (d == 0) out_ncs[k] = ncs;
    float nea = DECAYF * embed_avg[g] + (1.f - DECAYF) * es[g];
    out_nea[g] = nea;
    out_embed[g] = nea * (denom / (ncs + EPSF));
}

extern "C" void kernel_launch(void* const* d_in, const int* in_sizes, int n_in,
                              void* d_out, int out_size, void* d_ws, size_t ws_size,
                              hipStream_t stream) {
    const float* x = (const float*)d_in[0];
    const float* embed = (const float*)d_in[1];
    const float* cluster_size = (const float*)d_in[2];
    const float* embed_avg = (const float*)d_in[3];

    const int D = DD;
    const int T = in_sizes[0] / D;   // 32768
    const int K = in_sizes[2];       // 8192

    float* out = (float*)d_out;
    float* q = out;                                 // T*D
    float* idxo = q + (size_t)T * D;                // T
    float* dist = idxo + T;                         // T*K
    float* oe = dist + (size_t)T * K;               // K*D
    float* oncs = oe + (size_t)K * D;               // K
    float* onea = oncs + K;                         // K*D

    char* ws = (char*)d_ws;
    float* e2 = (float*)(ws + WS_E2);
    float* x2 = (float*)(ws + WS_X2);
    float* cs = (float*)(ws + WS_CS);
    float* sumcs = (float*)(ws + WS_SUM);
    unsigned long long* packed = (unsigned long long*)(ws + WS_PACK);
    float* es = (float*)(ws + WS_ES);

    (void)hipMemsetAsync(cs, 0, (size_t)K * sizeof(float), stream);
    (void)hipMemsetAsync(es, 0, (size_t)K * D * sizeof(float), stream);
    (void)hipMemsetAsync(packed, 0xFF, (size_t)T * sizeof(unsigned long long), stream);

    row_sumsq<<<K / 4, 256, 0, stream>>>(embed, e2, K);
    row_sumsq<<<T / 4, 256, 0, stream>>>(x, x2, T);
    sum_all<<<1, 256, 0, stream>>>(cluster_size, K, sumcs);

    dim3 dg(T / BM, K / BN);
    dist_kernel<<<dg, 256, 0, stream>>>(x, embed, x2, e2, dist, packed, K);

    assign_kernel<<<T / 2, 256, 0, stream>>>(x, embed, packed, q, idxo, cs, es);
    finalize_kernel<<<(K * D) / 256, 256, 0, stream>>>(cluster_size, embed_avg, cs, es,
                                                       sumcs, oe, oncs, onea, K, T);
}